// Round 1
// baseline (833.828 us; speedup 1.0000x reference)
//
#include <hip/hip_runtime.h>
#include <hip/hip_bf16.h>
#include <cstddef>

// Problem constants
#define BB   16
#define LL   2048
#define DD   1024
#define SS   64
#define HH   512
#define H3   1536
#define NCLS 3
#define NWG  16   // WGs per GRU layer: each owns 32 of 512 hidden dims, all batches
#define NTHR 384  // 6 waves: wave w computes gate-tile w (16 gates x 16 batches)

typedef _Float16 f16x8  __attribute__((ext_vector_type(8)));
typedef float    f32x4  __attribute__((ext_vector_type(4)));

static __device__ __forceinline__ unsigned short f2h(float f) {
    _Float16 h = (_Float16)f;
    union { _Float16 h; unsigned short u; } cv; cv.h = h; return cv.u;
}

// ---------------------------------------------------------------------------
// 1) Segment-mean pooling. One WG per (s,b); output (S,B,D) row r = s*16+b,
//    in fp32 (residual) AND f16 (GEMM input).
// ---------------------------------------------------------------------------
__global__ __launch_bounds__(256) void pool_kernel(
        const float* __restrict__ hs,      // (B, L, D)
        const int*   __restrict__ gidx,    // (B, L)
        float*       __restrict__ pooled,  // (S*B, D) fp32
        _Float16*    __restrict__ pooledh) // (S*B, D) f16
{
    const int r = blockIdx.x;
    const int b = r & 15;
    const int s = r >> 4;
    __shared__ int lst[LL];
    __shared__ int cnt;
    const int tid = threadIdx.x;
    if (tid == 0) cnt = 0;
    __syncthreads();
    const int* gi = gidx + b * LL;
    for (int l = tid; l < LL; l += 256) {
        if (gi[l] == s) { int p = atomicAdd(&cnt, 1); lst[p] = l; }
    }
    __syncthreads();
    const int c = cnt;
    const float* hb = hs + (size_t)b * LL * DD;
    const int d0 = tid * 4;
    float4 acc = make_float4(0.f, 0.f, 0.f, 0.f);
    for (int i = 0; i < c; ++i) {
        const float4 v = *(const float4*)(hb + (size_t)lst[i] * DD + d0);
        acc.x += v.x; acc.y += v.y; acc.z += v.z; acc.w += v.w;
    }
    const float inv = 1.0f / (float)c;
    float4 o = make_float4(acc.x * inv, acc.y * inv, acc.z * inv, acc.w * inv);
    *(float4*)(pooled + (size_t)r * DD + d0) = o;
    ushort4 oh;
    oh.x = f2h(o.x); oh.y = f2h(o.y); oh.z = f2h(o.z); oh.w = f2h(o.w);
    *(ushort4*)(pooledh + (size_t)r * DD + d0) = oh;
}

// ---------------------------------------------------------------------------
// 2) Fused fp32 -> f16 convert for all 4 GEMM weight matrices (1 dispatch).
//    Block ranges: [0,256) W_down, [256,640) W_ih0, [640,1024) W_ih1,
//    [1024,1280) W_lin1. Each block converts 2048 elements.
// ---------------------------------------------------------------------------
__global__ __launch_bounds__(256) void cvt4_kernel(
        const float* __restrict__ a, _Float16* __restrict__ da,
        const float* __restrict__ b, _Float16* __restrict__ db,
        const float* __restrict__ c, _Float16* __restrict__ dc,
        const float* __restrict__ d, _Float16* __restrict__ dd)
{
    int blk = blockIdx.x;
    const float* s; _Float16* t;
    if (blk < 256)       { s = a; t = da; }
    else if (blk < 640)  { s = b; t = db; blk -= 256; }
    else if (blk < 1024) { s = c; t = dc; blk -= 640; }
    else                 { s = d; t = dd; blk -= 1024; }
    const int i = (blk * 256 + threadIdx.x) * 8;
    const float4 v0 = *(const float4*)(s + i);
    const float4 v1 = *(const float4*)(s + i + 4);
    ushort4 u0, u1;
    u0.x = f2h(v0.x); u0.y = f2h(v0.y); u0.z = f2h(v0.z); u0.w = f2h(v0.w);
    u1.x = f2h(v1.x); u1.y = f2h(v1.y); u1.z = f2h(v1.z); u1.w = f2h(v1.w);
    *(ushort4*)(t + i)     = u0;
    *(ushort4*)(t + i + 4) = u1;
}

// ---------------------------------------------------------------------------
// 3) f16 MFMA GEMM: C[M,N] = A[M,K] @ W[N,K]^T + bias[N] (+resid, fp32 out)
//    or f16 out. 64x64 tile per WG (4 waves; wave w = 16-row strip), K-step 32.
// ---------------------------------------------------------------------------
template <bool F16OUT>
__global__ __launch_bounds__(256) void gemm_mfma_kernel(
        const _Float16* __restrict__ A,
        const _Float16* __restrict__ W,
        const float*    __restrict__ bias,
        const float*    __restrict__ resid,   // nullable, only for fp32 out
        void*           __restrict__ C,
        int M, int N, int K)
{
    const int tid  = threadIdx.x;
    const int wv   = tid >> 6;
    const int lane = tid & 63;
    const int m0 = blockIdx.y * 64 + wv * 16;
    const int n0 = blockIdx.x * 64;
    const int l15 = lane & 15;
    const int ko  = (lane >> 4) * 8;

    const _Float16* Ap = A + (size_t)(m0 + l15) * K + ko;
    const _Float16* Wp = W + (size_t)(n0 + l15) * K + ko;

    f32x4 acc[4] = {};
    for (int k0 = 0; k0 < K; k0 += 32) {
        const f16x8 a = *(const f16x8*)(Ap + k0);
#pragma unroll
        for (int nb = 0; nb < 4; ++nb) {
            const f16x8 bq = *(const f16x8*)(Wp + (size_t)nb * 16 * K + k0);
            acc[nb] = __builtin_amdgcn_mfma_f32_16x16x32_f16(a, bq, acc[nb], 0, 0, 0);
        }
    }
    const int crow = m0 + (lane >> 4) * 4;
#pragma unroll
    for (int nb = 0; nb < 4; ++nb) {
        const int col = n0 + nb * 16 + l15;
        const float bb = bias[col];
#pragma unroll
        for (int rg = 0; rg < 4; ++rg) {
            float v = acc[nb][rg] + bb;
            const size_t off = (size_t)(crow + rg) * N + col;
            if (F16OUT) {
                ((_Float16*)C)[off] = (_Float16)v;
            } else {
                if (resid) v += resid[off];
                ((float*)C)[off] = v;
            }
        }
    }
}

// ---------------------------------------------------------------------------
// 4) GRU recurrent layer v6: batched MFMA. 16 WGs (one per 32-dim h slice),
//    each computes its 96 gate rows for ALL 16 batches per step:
//    M=16(batch) x N=96(gates) x K=512 via mfma_f32_16x16x32_f16.
//    - per-wave weight fragments live in registers (loop-constant indexed)
//    - h_{t-1} staged in LDS with XOR swizzle (^(row&7)<<4) -> conflict-free
//      ds_read_b128 A-fragments
//    - fp32 recurrent state h_own stays thread-local (same numerics as v5)
//    - cross-WG handshake: agent-scope hbuf (f16 pairs) + per-WG flag;
//      16 WGs polling 16 flags (was 256 WGs -> coherence-point contention /16)
// ---------------------------------------------------------------------------
__global__ __launch_bounds__(NTHR) void gru_mfma_kernel(
        const _Float16* __restrict__ xW,    // (S*B, 1536) f16, row = t*16+b
        const float*    __restrict__ Whh,   // (1536, 512) fp32
        const float*    __restrict__ b_hh,  // (1536)
        _Float16*       __restrict__ ys,    // (S*B, 512) f16
        unsigned int*   __restrict__ hbuf,  // [2][16][256] u32 (f16 pairs)
        int*            __restrict__ hflag) // (16), pre-zeroed
{
    __shared__ __align__(16) _Float16 h_lds[BB * HH];       // 16 KB, swizzled
    __shared__ __align__(16) _Float16 xw_lds[3 * BB * 32];  // 3 KB
    __shared__ float dots[96 * 20];                         // 7.5 KB, stride 20

    const int p    = blockIdx.x;        // h-dim slice [p*32, p*32+32)
    const int tid  = threadIdx.x;
    const int wv   = tid >> 6;          // 0..5 — this wave's gate tile
    const int lane = tid & 63;
    const int l15  = lane & 15;
    const int kg   = lane >> 4;         // 0..3

    // ---- init: zero h_lds (t=0 MFMA input); load weight frags to regs ----
    {
        const uint4 z = {0u, 0u, 0u, 0u};
        for (int i = tid; i < BB * HH / 8; i += NTHR)
            *(uint4*)&h_lds[i * 8] = z;
    }
    // wave wv covers global gate rows grow = (wv>>1)*512 + p*32 + (wv&1)*16 + n
    const int grow = (wv >> 1) * HH + p * 32 + (wv & 1) * 16 + l15;
    const float bias_r = b_hh[grow];
    f16x8 wB[16];                       // B-frag per K-step (n=l15, k=kg*8+j)
    {
        const float* wr = Whh + (size_t)grow * HH + kg * 8;
#pragma unroll
        for (int ks = 0; ks < 16; ++ks) {
            const float4 f0 = *(const float4*)(wr + ks * 32);
            const float4 f1 = *(const float4*)(wr + ks * 32 + 4);
            f16x8 v;
            v[0] = (_Float16)f0.x; v[1] = (_Float16)f0.y;
            v[2] = (_Float16)f0.z; v[3] = (_Float16)f0.w;
            v[4] = (_Float16)f1.x; v[5] = (_Float16)f1.y;
            v[6] = (_Float16)f1.z; v[7] = (_Float16)f1.w;
            wB[ks] = v;
        }
    }
    float h_own0 = 0.f, h_own1 = 0.f;   // fp32 carried h (threads 0..255)
    __syncthreads();

    for (int t = 0; t < SS; ++t) {
        // ---- xW prefetch: no h dependency, overlaps the flag wait ----
        uint4 xwv = {0u, 0u, 0u, 0u};
        if (tid < 192) {
            const int gate = tid >> 6;
            const int b    = (tid >> 2) & 15;
            const int j0   = (tid & 3) * 8;
            xwv = *(const uint4*)(xW + (size_t)(t * BB + b) * H3
                                  + gate * HH + p * 32 + j0);
        }
        // ---- wait for h_{t-1}, reload into LDS (swizzled) ----
        if (t > 0) {
            if (tid < 64) {
                const int* fp = hflag + (tid & 15);
                for (;;) {
                    const int v = __hip_atomic_load(fp, __ATOMIC_RELAXED,
                                                    __HIP_MEMORY_SCOPE_AGENT);
                    if (__all(v >= t)) break;
                    __builtin_amdgcn_s_sleep(1);
                }
            }
            __syncthreads();                                   // (1)
            const unsigned long long* src =
                (const unsigned long long*)(hbuf + ((t - 1) & 1) * 4096);
            for (int i = tid; i < 2048; i += NTHR) {
                const unsigned long long v =
                    __hip_atomic_load(src + i, __ATOMIC_RELAXED,
                                      __HIP_MEMORY_SCOPE_AGENT);
                const int ps = i >> 7;          // producer slice
                const int b  = (i >> 3) & 15;   // batch
                const int dq = i & 7;           // 4-dim quad
                int addr = b * 1024 + ps * 64 + dq * 8;
                addr ^= (b & 7) << 4;
                *(unsigned long long*)((char*)h_lds + addr) = v;
            }
        }
        if (tid < 192) *(uint4*)&xw_lds[tid * 8] = xwv;
        __syncthreads();                                       // (2)

        // ---- MFMA: this wave's 16 gates x 16 batches over K=512 ----
        f32x4 acc = {};
#pragma unroll
        for (int ks = 0; ks < 16; ++ks) {
            int aaddr = l15 * 1024 + ks * 64 + kg * 16;        // row m=l15
            aaddr ^= (l15 & 7) << 4;
            const f16x8 a = *(const f16x8*)((char*)h_lds + aaddr);
            acc = __builtin_amdgcn_mfma_f32_16x16x32_f16(a, wB[ks], acc, 0, 0, 0);
        }
        {   // D: col=l15 (gate), row=kg*4+rg (batch); add b_hh here
            const int g  = wv * 16 + l15;
            const int b0 = kg * 4;
#pragma unroll
            for (int rg = 0; rg < 4; ++rg)
                dots[g * 20 + b0 + rg] = acc[rg] + bias_r;
        }
        __syncthreads();                                       // (3)

        // ---- gate math: 512 h values, threads 0..255 own (b, j2..j2+1) ----
        if (tid < 256) {
            const int b  = tid >> 4;
            const int j2 = (tid & 15) * 2;
            float hn[2];
#pragma unroll
            for (int u = 0; u < 2; ++u) {
                const int j  = j2 + u;
                const float ar = dots[j * 20 + b];
                const float az = dots[(32 + j) * 20 + b];
                const float an = dots[(64 + j) * 20 + b];
                const float xr = (float)xw_lds[0 * HH + b * 32 + j];
                const float xz = (float)xw_lds[1 * HH + b * 32 + j];
                const float xn = (float)xw_lds[2 * HH + b * 32 + j];
                const float hp = (u == 0) ? h_own0 : h_own1;
                const float rg = 1.f / (1.f + __expf(-(xr + ar)));
                const float zg = 1.f / (1.f + __expf(-(xz + az)));
                const float nn = xn + rg * an;
                const float e  = __expf(-2.f * nn);
                const float tg = (1.f - e) / (1.f + e);        // tanh
                hn[u] = (1.f - zg) * tg + zg * hp;
            }
            h_own0 = hn[0]; h_own1 = hn[1];
            const unsigned int pk = (unsigned int)f2h(hn[0])
                                  | ((unsigned int)f2h(hn[1]) << 16);
            *(unsigned int*)(ys + (size_t)(t * BB + b) * HH + p * 32 + j2) = pk;
            __hip_atomic_store(
                hbuf + (t & 1) * 4096 + p * 256 + b * 16 + (j2 >> 1),
                pk, __ATOMIC_RELAXED, __HIP_MEMORY_SCOPE_AGENT);
        }
        // drain stores (per wave), barrier, then single flag store
        __builtin_amdgcn_s_waitcnt(0);
        __syncthreads();                                       // (4)
        if (tid == 0)
            __hip_atomic_store(hflag + p, t + 1, __ATOMIC_RELAXED,
                               __HIP_MEMORY_SCOPE_AGENT);
    }
}

// ---------------------------------------------------------------------------
// 5) Fused LayerNorm + classification head. One WG per output row.
// ---------------------------------------------------------------------------
__global__ __launch_bounds__(256) void ln_head_kernel(
        const float* __restrict__ X,      // (S*B, D), row = s*16+b
        const float* __restrict__ gamma,
        const float* __restrict__ beta,
        const float* __restrict__ Wh,     // (3, 1024)
        const float* __restrict__ bh,     // (3)
        float*       __restrict__ out)    // (B*S, 3)
{
    __shared__ float red[12];
    const int r  = blockIdx.x;            // b*64 + s
    const int bI = r >> 6;
    const int s  = r & 63;
    const float* x = X + (size_t)(s * BB + bI) * DD;
    const int tid = threadIdx.x;
    const float4 v = *(const float4*)(x + tid * 4);
    float sum = v.x + v.y + v.z + v.w;
    float ss  = v.x * v.x + v.y * v.y + v.z * v.z + v.w * v.w;
#pragma unroll
    for (int o = 32; o > 0; o >>= 1) {
        sum += __shfl_down(sum, o, 64);
        ss  += __shfl_down(ss,  o, 64);
    }
    const int lane = tid & 63, w = tid >> 6;
    if (lane == 0) { red[w] = sum; red[4 + w] = ss; }
    __syncthreads();
    const float tsum = red[0] + red[1] + red[2] + red[3];
    const float tss  = red[4] + red[5] + red[6] + red[7];
    const float mu  = tsum * (1.f / (float)DD);
    const float var = tss * (1.f / (float)DD) - mu * mu;
    const float inv = rsqrtf(var + 1e-5f);
    const float4 g  = *(const float4*)(gamma + tid * 4);
    const float4 be = *(const float4*)(beta + tid * 4);
    float y0 = (v.x - mu) * inv * g.x + be.x;
    float y1 = (v.y - mu) * inv * g.y + be.y;
    float y2 = (v.z - mu) * inv * g.z + be.z;
    float y3 = (v.w - mu) * inv * g.w + be.w;
    const float4 w0 = *(const float4*)(Wh + 0 * DD + tid * 4);
    const float4 w1 = *(const float4*)(Wh + 1 * DD + tid * 4);
    const float4 w2 = *(const float4*)(Wh + 2 * DD + tid * 4);
    float p0 = y0 * w0.x + y1 * w0.y + y2 * w0.z + y3 * w0.w;
    float p1 = y0 * w1.x + y1 * w1.y + y2 * w1.z + y3 * w1.w;
    float p2 = y0 * w2.x + y1 * w2.y + y2 * w2.z + y3 * w2.w;
#pragma unroll
    for (int o = 32; o > 0; o >>= 1) {
        p0 += __shfl_down(p0, o, 64);
        p1 += __shfl_down(p1, o, 64);
        p2 += __shfl_down(p2, o, 64);
    }
    __syncthreads();
    if (lane == 0) { red[w] = p0; red[4 + w] = p1; red[8 + w] = p2; }
    __syncthreads();
    if (tid == 0) {
        out[(size_t)r * NCLS + 0] = red[0] + red[1] + red[2]  + red[3]  + bh[0];
        out[(size_t)r * NCLS + 1] = red[4] + red[5] + red[6]  + red[7]  + bh[1];
        out[(size_t)r * NCLS + 2] = red[8] + red[9] + red[10] + red[11] + bh[2];
    }
}

// ---------------------------------------------------------------------------
extern "C" void kernel_launch(void* const* d_in, const int* in_sizes, int n_in,
                              void* d_out, int out_size, void* d_ws, size_t ws_size,
                              hipStream_t stream) {
    const float* hs      = (const float*)d_in[0];
    const float* W_down  = (const float*)d_in[1];
    const float* b_down  = (const float*)d_in[2];
    const float* W_ih0   = (const float*)d_in[3];
    const float* W_hh0   = (const float*)d_in[4];
    const float* b_ih0   = (const float*)d_in[5];
    const float* b_hh0   = (const float*)d_in[6];
    const float* W_ih1   = (const float*)d_in[7];
    const float* W_hh1   = (const float*)d_in[8];
    const float* b_ih1   = (const float*)d_in[9];
    const float* b_hh1   = (const float*)d_in[10];
    const float* W_lin1  = (const float*)d_in[11];
    const float* b_lin1  = (const float*)d_in[12];
    const float* gamma   = (const float*)d_in[13];
    const float* beta    = (const float*)d_in[14];
    const float* W_head  = (const float*)d_in[15];
    const float* b_head  = (const float*)d_in[16];
    const int*   gidx    = (const int*)d_in[17];
    float* out = (float*)d_out;

    char* ws = (char*)d_ws;
    const size_t MB = (size_t)1 << 20;
    float*        pooled   = (float*)(ws);                        // 4 MB fp32
    _Float16*     pooledh  = (_Float16*)(ws + 4 * MB);            // 2 MB
    _Float16*     xd_h     = (_Float16*)(ws + 6 * MB);            // 1 MB (reused as ys0_h)
    _Float16*     xW_h     = (_Float16*)(ws + 7 * MB);            // 3 MB
    _Float16*     ys1_h    = (_Float16*)(ws + 10 * MB);           // 1 MB
    float*        xln      = (float*)(ws + 11 * MB);              // 4 MB
    _Float16*     wdown_h  = (_Float16*)(ws + 18 * MB);           // 1 MB
    _Float16*     wih0_h   = (_Float16*)(ws + 19 * MB);           // 1.5 MB
    _Float16*     wih1_h   = (_Float16*)(ws + 19 * MB + 1536 * 1024); // 1.5 MB
    _Float16*     wlin1_h  = (_Float16*)(ws + 22 * MB);           // 1 MB
    unsigned int* hbuf     = (unsigned int*)(ws + 23 * MB);       // 32 KB
    int*          hflag    = (int*)(ws + 23 * MB + (64 << 10));   // 128 B
    _Float16*     ys0_h    = xd_h;                                // reuse (xd dead after ih0)

    // zero the flags (ws is poisoned before every launch)
    hipMemsetAsync(hflag, 0, 2 * NWG * sizeof(int), stream);

    // 1) pooling: fp32 residual + f16 GEMM input, layout (S,B,D)
    pool_kernel<<<BB * SS, 256, 0, stream>>>(hs, gidx, pooled, pooledh);

    // 2) convert all GEMM weights to f16 (single fused dispatch)
    cvt4_kernel<<<1280, 256, 0, stream>>>(W_down, wdown_h, W_ih0, wih0_h,
                                          W_ih1, wih1_h, W_lin1, wlin1_h);

    // 3) down-projection: xd = pooled @ W_down^T + b_down  (f16 out)
    gemm_mfma_kernel<true><<<dim3(HH / 64, (SS * BB) / 64), 256, 0, stream>>>(
        pooledh, wdown_h, b_down, nullptr, xd_h, SS * BB, HH, DD);

    // 4) layer-0 input projection: xW = xd @ W_ih0^T + b_ih0  (f16 out)
    gemm_mfma_kernel<true><<<dim3(H3 / 64, (SS * BB) / 64), 256, 0, stream>>>(
        xd_h, wih0_h, b_ih0, nullptr, xW_h, SS * BB, H3, HH);

    // 5) layer-0 recurrence (batched MFMA, 16 WGs)
    gru_mfma_kernel<<<NWG, NTHR, 0, stream>>>(
        xW_h, W_hh0, b_hh0, ys0_h, hbuf, hflag);

    // 6) layer-1 input projection
    gemm_mfma_kernel<true><<<dim3(H3 / 64, (SS * BB) / 64), 256, 0, stream>>>(
        ys0_h, wih1_h, b_ih1, nullptr, xW_h, SS * BB, H3, HH);

    // 7) layer-1 recurrence (fresh flag block)
    gru_mfma_kernel<<<NWG, NTHR, 0, stream>>>(
        xW_h, W_hh1, b_hh1, ys1_h, hbuf, hflag + NWG);

    // 8) up-projection + residual: xln = pooled + ys1 @ W_lin1^T + b_lin1 (fp32)
    gemm_mfma_kernel<false><<<dim3(DD / 64, (SS * BB) / 64), 256, 0, stream>>>(
        ys1_h, wlin1_h, b_lin1, pooled, xln, SS * BB, DD, HH);

    // 9) LayerNorm + head
    ln_head_kernel<<<BB * SS, 256, 0, stream>>>(xln, gamma, beta, W_head, b_head, out);
}

// Round 2
// 584.448 us; speedup vs baseline: 1.4267x; 1.4267x over previous
//
#include <hip/hip_runtime.h>
#include <hip/hip_bf16.h>
#include <cstddef>

// Problem constants
#define BB   16
#define LL   2048
#define DD   1024
#define SS   64
#define HH   512
#define H3   1536
#define NCLS 3
#define GPB  16   // WGs per batch in the GRU (each owns 32 of 512 hidden dims)

typedef _Float16 half2_t __attribute__((ext_vector_type(2)));
typedef _Float16 f16x8  __attribute__((ext_vector_type(8)));
typedef float    f32x4  __attribute__((ext_vector_type(4)));

static __device__ __forceinline__ half2_t u2h2(unsigned int u) {
    union { unsigned int u; half2_t h; } cv; cv.u = u; return cv.h;
}
static __device__ __forceinline__ unsigned short f2h(float f) {
    _Float16 h = (_Float16)f;
    union { _Float16 h; unsigned short u; } cv; cv.h = h; return cv.u;
}

// ---------------------------------------------------------------------------
// 1) Segment-mean pooling. One WG per (s,b); output (S,B,D) row r = s*16+b,
//    in fp32 (residual) AND f16 (GEMM input).
// ---------------------------------------------------------------------------
__global__ __launch_bounds__(256) void pool_kernel(
        const float* __restrict__ hs,      // (B, L, D)
        const int*   __restrict__ gidx,    // (B, L)
        float*       __restrict__ pooled,  // (S*B, D) fp32
        _Float16*    __restrict__ pooledh) // (S*B, D) f16
{
    const int r = blockIdx.x;
    const int b = r & 15;
    const int s = r >> 4;
    __shared__ int lst[LL];
    __shared__ int cnt;
    const int tid = threadIdx.x;
    if (tid == 0) cnt = 0;
    __syncthreads();
    const int* gi = gidx + b * LL;
    for (int l = tid; l < LL; l += 256) {
        if (gi[l] == s) { int p = atomicAdd(&cnt, 1); lst[p] = l; }
    }
    __syncthreads();
    const int c = cnt;
    const float* hb = hs + (size_t)b * LL * DD;
    const int d0 = tid * 4;
    float4 acc = make_float4(0.f, 0.f, 0.f, 0.f);
    for (int i = 0; i < c; ++i) {
        const float4 v = *(const float4*)(hb + (size_t)lst[i] * DD + d0);
        acc.x += v.x; acc.y += v.y; acc.z += v.z; acc.w += v.w;
    }
    const float inv = 1.0f / (float)c;
    float4 o = make_float4(acc.x * inv, acc.y * inv, acc.z * inv, acc.w * inv);
    *(float4*)(pooled + (size_t)r * DD + d0) = o;
    ushort4 oh;
    oh.x = f2h(o.x); oh.y = f2h(o.y); oh.z = f2h(o.z); oh.w = f2h(o.w);
    *(ushort4*)(pooledh + (size_t)r * DD + d0) = oh;
}

// ---------------------------------------------------------------------------
// 2) prep kernel: fused weight conversion + W_hh packing (one dispatch).
//    Blocks [0,1280):  fp32->f16 convert of W_down/W_ih0/W_ih1/W_lin1.
//    Blocks [1280,2048): pack W_hh0 -> wp0 (256 x 1536 u32, f16 k-pairs).
//    Blocks [2048,2816): pack W_hh1 -> wp1.
// ---------------------------------------------------------------------------
__global__ __launch_bounds__(256) void prep_kernel(
        const float* __restrict__ a, _Float16* __restrict__ da,
        const float* __restrict__ b, _Float16* __restrict__ db,
        const float* __restrict__ c, _Float16* __restrict__ dc,
        const float* __restrict__ d, _Float16* __restrict__ dd,
        const float* __restrict__ Whh0, unsigned int* __restrict__ wp0,
        const float* __restrict__ Whh1, unsigned int* __restrict__ wp1)
{
    __shared__ float tb[32][33];
    const int tid = threadIdx.x;
    int blk = blockIdx.x;
    if (blk < 1280) {
        const float* s; _Float16* t;
        if (blk < 256)       { s = a; t = da; }
        else if (blk < 640)  { s = b; t = db; blk -= 256; }
        else if (blk < 1024) { s = c; t = dc; blk -= 640; }
        else                 { s = d; t = dd; blk -= 1024; }
        const int i = (blk * 256 + tid) * 8;
        const float4 v0 = *(const float4*)(s + i);
        const float4 v1 = *(const float4*)(s + i + 4);
        ushort4 u0, u1;
        u0.x = f2h(v0.x); u0.y = f2h(v0.y); u0.z = f2h(v0.z); u0.w = f2h(v0.w);
        u1.x = f2h(v1.x); u1.y = f2h(v1.y); u1.z = f2h(v1.z); u1.w = f2h(v1.w);
        *(ushort4*)(t + i)     = u0;
        *(ushort4*)(t + i + 4) = u1;
        return;
    }
    const float*  W;
    unsigned int* Wp;
    int idx;
    if (blk < 2048) { W = Whh0; Wp = wp0; idx = blk - 1280; }
    else            { W = Whh1; Wp = wp1; idx = blk - 2048; }
    const int bk = idx & 15;            // k-block (16)
    const int bg = idx >> 4;            // g-block (48)
    const int k0 = bk * 32, g0 = bg * 32;
    const int tx = tid & 31, ty = tid >> 5;
    for (int i = ty; i < 32; i += 8)
        tb[i][tx] = W[(size_t)(g0 + i) * HH + k0 + tx];
    __syncthreads();
    for (int i = ty; i < 16; i += 8) {
        const float lo = tb[tx][2 * i];
        const float hi = tb[tx][2 * i + 1];
        const unsigned int pk = (unsigned int)f2h(lo) | ((unsigned int)f2h(hi) << 16);
        Wp[(size_t)(k0 / 2 + i) * H3 + g0 + tx] = pk;
    }
}

// ---------------------------------------------------------------------------
// 3) f16 MFMA GEMM: C[M,N] = A[M,K] @ W[N,K]^T + bias[N] (+resid, fp32 out)
//    or f16 out. 64x64 tile per WG (4 waves; wave w = 16-row strip), K-step 32.
// ---------------------------------------------------------------------------
template <bool F16OUT>
__global__ __launch_bounds__(256) void gemm_mfma_kernel(
        const _Float16* __restrict__ A,
        const _Float16* __restrict__ W,
        const float*    __restrict__ bias,
        const float*    __restrict__ resid,   // nullable, only for fp32 out
        void*           __restrict__ C,
        int M, int N, int K)
{
    const int tid  = threadIdx.x;
    const int wv   = tid >> 6;
    const int lane = tid & 63;
    const int m0 = blockIdx.y * 64 + wv * 16;
    const int n0 = blockIdx.x * 64;
    const int l15 = lane & 15;
    const int ko  = (lane >> 4) * 8;

    const _Float16* Ap = A + (size_t)(m0 + l15) * K + ko;
    const _Float16* Wpt = W + (size_t)(n0 + l15) * K + ko;

    f32x4 acc[4] = {};
    for (int k0 = 0; k0 < K; k0 += 32) {
        const f16x8 av = *(const f16x8*)(Ap + k0);
#pragma unroll
        for (int nb = 0; nb < 4; ++nb) {
            const f16x8 bq = *(const f16x8*)(Wpt + (size_t)nb * 16 * K + k0);
            acc[nb] = __builtin_amdgcn_mfma_f32_16x16x32_f16(av, bq, acc[nb], 0, 0, 0);
        }
    }
    const int crow = m0 + (lane >> 4) * 4;
#pragma unroll
    for (int nb = 0; nb < 4; ++nb) {
        const int col = n0 + nb * 16 + l15;
        const float bb = bias[col];
#pragma unroll
        for (int rg = 0; rg < 4; ++rg) {
            float v = acc[nb][rg] + bb;
            const size_t off = (size_t)(crow + rg) * N + col;
            if (F16OUT) {
                ((_Float16*)C)[off] = (_Float16)v;
            } else {
                if (resid) v += resid[off];
                ((float*)C)[off] = v;
            }
        }
    }
}

// ---------------------------------------------------------------------------
// 4) GRU recurrent layer v7: v5 structure (256 WGs = (b,p); 96-row weight
//    slice in registers; 1 KB h-exchange) with a ONE-round-trip handshake:
//    each 8-byte hbuf word is {h pair (f16x2), tag = t+1}, stored with a
//    single-copy-atomic dwordx2. Consumers poll their own word — the poll IS
//    the data load. No flag array, no producer store drain, 2 barriers/step.
//    Overwrite safety: producer reaches step t+2's write only after barrier
//    A(t+2), which needs all 256 threads to observe every slice's t+1 tag,
//    published only after those producers finished reading slot t&1.
// ---------------------------------------------------------------------------
__global__ __launch_bounds__(256) void gru_layer7_kernel(
        const _Float16*     __restrict__ xW,    // (S*B, 1536) f16, row = t*16+b
        const unsigned int* __restrict__ Wp,    // (256, 1536) packed f16 pairs
        const float*        __restrict__ b_hh,  // (1536)
        _Float16*           __restrict__ ys,    // (S*B, 512) f16
        unsigned long long* __restrict__ hbuf)  // [2][16][256] {pk, tag}
{
    __shared__ __align__(16) unsigned int hls[264];  // halves at 0 / 132 (4-bank shift)
    __shared__ float dots[96];

    const int wg  = blockIdx.x;
    const int b   = wg & 15;
    const int p   = wg >> 4;
    const int tid = threadIdx.x;

    // dot-thread assignment: tid = 2*r + half, r = gate*32 + jl (tid<192)
    const int r    = tid >> 1;
    const int half = tid & 1;
    const int gate = r >> 5;
    const int jl   = r & 31;
    const int col  = gate * HH + p * 32 + jl;

    float bias = 0.f;
    unsigned int wreg[128];                    // this thread's weight half-row
    if (tid < 192) {
        bias = b_hh[col];
#pragma unroll
        for (int i = 0; i < 128; ++i)
            wreg[i] = Wp[(size_t)(half * 128 + i) * H3 + col];
    }

    // zero hls for the t=0 dots (h_{-1} = 0); cover both padded halves
    hls[tid] = 0u;
    if (tid < 8) hls[256 + tid] = 0u;

    float h_own = 0.f;                         // fp32 carried h (tid<32)
    __syncthreads();

    for (int t = 0; t < SS; ++t) {
        const int row = t * BB + b;
        float xr = 0.f, xz = 0.f, xn = 0.f;
        if (tid < 32) {                        // issued early; hides under poll
            const int j = p * 32 + tid;
            xr = (float)xW[(size_t)row * H3 + j];
            xz = (float)xW[(size_t)row * H3 + HH + j];
            xn = (float)xW[(size_t)row * H3 + 2 * HH + j];
        }

        // ---- poll-load h_{t-1}: each thread owns one tagged 8-B word ----
        if (t > 0) {
            const unsigned long long* src =
                hbuf + ((size_t)(((t - 1) & 1) * BB + b)) * 256 + tid;
            unsigned long long v;
            for (;;) {
                v = __hip_atomic_load(src, __ATOMIC_RELAXED,
                                      __HIP_MEMORY_SCOPE_AGENT);
                if ((unsigned int)(v >> 32) == (unsigned int)t) break;
                __builtin_amdgcn_s_sleep(1);
            }
            hls[(tid >> 7) * 132 + (tid & 127)] = (unsigned int)v;
        }
        __syncthreads();                                   // (A)

        // ---- 96 dots of length 512: register weights x broadcast-LDS h ----
        if (tid < 192) {
            float a0 = 0.f, a1 = 0.f, a2 = 0.f, a3 = 0.f;
            const uint4* hp = (const uint4*)&hls[half * 132];
#pragma unroll
            for (int i = 0; i < 32; ++i) {
                const uint4 hv = hp[i];
                a0 = __builtin_amdgcn_fdot2(u2h2(wreg[4 * i + 0]), u2h2(hv.x), a0, false);
                a1 = __builtin_amdgcn_fdot2(u2h2(wreg[4 * i + 1]), u2h2(hv.y), a1, false);
                a2 = __builtin_amdgcn_fdot2(u2h2(wreg[4 * i + 2]), u2h2(hv.z), a2, false);
                a3 = __builtin_amdgcn_fdot2(u2h2(wreg[4 * i + 3]), u2h2(hv.w), a3, false);
            }
            float acc = (a0 + a1) + (a2 + a3);
            acc += __shfl_xor(acc, 1, 64);     // combine k-halves
            if (half == 0) dots[r] = acc + bias;
        }
        __syncthreads();                                   // (B)

        // ---- gate math + h update for this WG's 32 dims (wave 0) ----
        if (tid < 32) {
            const float ar = dots[tid];
            const float az = dots[32 + tid];
            const float an = dots[64 + tid];
            const float rg = 1.f / (1.f + __expf(-(xr + ar)));
            const float zg = 1.f / (1.f + __expf(-(xz + az)));
            const float nn = xn + rg * an;
            const float e  = __expf(-2.f * nn);
            const float ng = (1.f - e) / (1.f + e);          // tanh
            const float hnew = (1.f - zg) * ng + zg * h_own;
            h_own = hnew;
            const int j = p * 32 + tid;
            ys[(size_t)row * HH + j] = (_Float16)hnew;
            const float other = __shfl_xor(hnew, 1, 64);
            if ((tid & 1) == 0) {
                const unsigned int pk = (unsigned int)f2h(hnew)
                                      | ((unsigned int)f2h(other) << 16);
                const unsigned long long val =
                    ((unsigned long long)(unsigned int)(t + 1) << 32) | pk;
                __hip_atomic_store(
                    hbuf + ((size_t)((t & 1) * BB + b)) * 256 + p * 16 + (tid >> 1),
                    val, __ATOMIC_RELAXED, __HIP_MEMORY_SCOPE_AGENT);
            }
        }
        // no trailing barrier: hls(t+1) writes are post-B(t) in program
        // order; xW/dots hazards are covered by A(t+1)/B(t+1).
    }
}

// ---------------------------------------------------------------------------
// 5) Fused LayerNorm + classification head. One WG per output row.
// ---------------------------------------------------------------------------
__global__ __launch_bounds__(256) void ln_head_kernel(
        const float* __restrict__ X,      // (S*B, D), row = s*16+b
        const float* __restrict__ gamma,
        const float* __restrict__ beta,
        const float* __restrict__ Wh,     // (3, 1024)
        const float* __restrict__ bh,     // (3)
        float*       __restrict__ out)    // (B*S, 3)
{
    __shared__ float red[12];
    const int r  = blockIdx.x;            // b*64 + s
    const int bI = r >> 6;
    const int s  = r & 63;
    const float* x = X + (size_t)(s * BB + bI) * DD;
    const int tid = threadIdx.x;
    const float4 v = *(const float4*)(x + tid * 4);
    float sum = v.x + v.y + v.z + v.w;
    float ss  = v.x * v.x + v.y * v.y + v.z * v.z + v.w * v.w;
#pragma unroll
    for (int o = 32; o > 0; o >>= 1) {
        sum += __shfl_down(sum, o, 64);
        ss  += __shfl_down(ss,  o, 64);
    }
    const int lane = tid & 63, w = tid >> 6;
    if (lane == 0) { red[w] = sum; red[4 + w] = ss; }
    __syncthreads();
    const float tsum = red[0] + red[1] + red[2] + red[3];
    const float tss  = red[4] + red[5] + red[6] + red[7];
    const float mu  = tsum * (1.f / (float)DD);
    const float var = tss * (1.f / (float)DD) - mu * mu;
    const float inv = rsqrtf(var + 1e-5f);
    const float4 g  = *(const float4*)(gamma + tid * 4);
    const float4 be = *(const float4*)(beta + tid * 4);
    float y0 = (v.x - mu) * inv * g.x + be.x;
    float y1 = (v.y - mu) * inv * g.y + be.y;
    float y2 = (v.z - mu) * inv * g.z + be.z;
    float y3 = (v.w - mu) * inv * g.w + be.w;
    const float4 w0 = *(const float4*)(Wh + 0 * DD + tid * 4);
    const float4 w1 = *(const float4*)(Wh + 1 * DD + tid * 4);
    const float4 w2 = *(const float4*)(Wh + 2 * DD + tid * 4);
    float p0 = y0 * w0.x + y1 * w0.y + y2 * w0.z + y3 * w0.w;
    float p1 = y0 * w1.x + y1 * w1.y + y2 * w1.z + y3 * w1.w;
    float p2 = y0 * w2.x + y1 * w2.y + y2 * w2.z + y3 * w2.w;
#pragma unroll
    for (int o = 32; o > 0; o >>= 1) {
        p0 += __shfl_down(p0, o, 64);
        p1 += __shfl_down(p1, o, 64);
        p2 += __shfl_down(p2, o, 64);
    }
    __syncthreads();
    if (lane == 0) { red[w] = p0; red[4 + w] = p1; red[8 + w] = p2; }
    __syncthreads();
    if (tid == 0) {
        out[(size_t)r * NCLS + 0] = red[0] + red[1] + red[2]  + red[3]  + bh[0];
        out[(size_t)r * NCLS + 1] = red[4] + red[5] + red[6]  + red[7]  + bh[1];
        out[(size_t)r * NCLS + 2] = red[8] + red[9] + red[10] + red[11] + bh[2];
    }
}

// ---------------------------------------------------------------------------
extern "C" void kernel_launch(void* const* d_in, const int* in_sizes, int n_in,
                              void* d_out, int out_size, void* d_ws, size_t ws_size,
                              hipStream_t stream) {
    const float* hs      = (const float*)d_in[0];
    const float* W_down  = (const float*)d_in[1];
    const float* b_down  = (const float*)d_in[2];
    const float* W_ih0   = (const float*)d_in[3];
    const float* W_hh0   = (const float*)d_in[4];
    const float* b_ih0   = (const float*)d_in[5];
    const float* b_hh0   = (const float*)d_in[6];
    const float* W_ih1   = (const float*)d_in[7];
    const float* W_hh1   = (const float*)d_in[8];
    const float* b_ih1   = (const float*)d_in[9];
    const float* b_hh1   = (const float*)d_in[10];
    const float* W_lin1  = (const float*)d_in[11];
    const float* b_lin1  = (const float*)d_in[12];
    const float* gamma   = (const float*)d_in[13];
    const float* beta    = (const float*)d_in[14];
    const float* W_head  = (const float*)d_in[15];
    const float* b_head  = (const float*)d_in[16];
    const int*   gidx    = (const int*)d_in[17];
    float* out = (float*)d_out;

    char* ws = (char*)d_ws;
    const size_t MB = (size_t)1 << 20;
    float*        pooled   = (float*)(ws);                        // 4 MB fp32
    _Float16*     pooledh  = (_Float16*)(ws + 4 * MB);            // 2 MB
    _Float16*     xd_h     = (_Float16*)(ws + 6 * MB);            // 1 MB (reused as ys0_h)
    _Float16*     xW_h     = (_Float16*)(ws + 7 * MB);            // 3 MB
    _Float16*     ys1_h    = (_Float16*)(ws + 10 * MB);           // 1 MB
    float*        xln      = (float*)(ws + 11 * MB);              // 4 MB
    unsigned int* wp0      = (unsigned int*)(ws + 15 * MB);       // 1.5 MB
    unsigned int* wp1      = (unsigned int*)(ws + 15 * MB + 1536 * 1024); // 1.5 MB
    _Float16*     wdown_h  = (_Float16*)(ws + 18 * MB);           // 1 MB
    _Float16*     wih0_h   = (_Float16*)(ws + 19 * MB);           // 1.5 MB
    _Float16*     wih1_h   = (_Float16*)(ws + 19 * MB + 1536 * 1024); // 1.5 MB
    _Float16*     wlin1_h  = (_Float16*)(ws + 22 * MB);           // 1 MB
    unsigned long long* hbuf0 = (unsigned long long*)(ws + 23 * MB); // 64 KB
    unsigned long long* hbuf1 = hbuf0 + 2 * BB * 256;                // 64 KB
    _Float16*     ys0_h    = xd_h;                                // reuse (xd dead after ih0)

    // zero the tagged h-exchange buffers (ws is poisoned before every launch;
    // garbage could alias a valid tag). 128 KB total.
    hipMemsetAsync(hbuf0, 0, 2 * 2 * BB * 256 * sizeof(unsigned long long), stream);

    // 1) pooling: fp32 residual + f16 GEMM input, layout (S,B,D)
    pool_kernel<<<BB * SS, 256, 0, stream>>>(hs, gidx, pooled, pooledh);

    // 2) fused weight prep: f16 converts + W_hh packing (one dispatch)
    prep_kernel<<<2816, 256, 0, stream>>>(W_down, wdown_h, W_ih0, wih0_h,
                                          W_ih1, wih1_h, W_lin1, wlin1_h,
                                          W_hh0, wp0, W_hh1, wp1);

    // 3) down-projection: xd = pooled @ W_down^T + b_down  (f16 out)
    gemm_mfma_kernel<true><<<dim3(HH / 64, (SS * BB) / 64), 256, 0, stream>>>(
        pooledh, wdown_h, b_down, nullptr, xd_h, SS * BB, HH, DD);

    // 4) layer-0 input projection: xW = xd @ W_ih0^T + b_ih0  (f16 out)
    gemm_mfma_kernel<true><<<dim3(H3 / 64, (SS * BB) / 64), 256, 0, stream>>>(
        xd_h, wih0_h, b_ih0, nullptr, xW_h, SS * BB, H3, HH);

    // 5) layer-0 recurrence
    gru_layer7_kernel<<<BB * GPB, 256, 0, stream>>>(
        xW_h, wp0, b_hh0, ys0_h, hbuf0);

    // 6) layer-1 input projection
    gemm_mfma_kernel<true><<<dim3(H3 / 64, (SS * BB) / 64), 256, 0, stream>>>(
        ys0_h, wih1_h, b_ih1, nullptr, xW_h, SS * BB, H3, HH);

    // 7) layer-1 recurrence (own zeroed buffer)
    gru_layer7_kernel<<<BB * GPB, 256, 0, stream>>>(
        xW_h, wp1, b_hh1, ys1_h, hbuf1);

    // 8) up-projection + residual: xln = pooled + ys1 @ W_lin1^T + b_lin1 (fp32)
    gemm_mfma_kernel<false><<<dim3(DD / 64, (SS * BB) / 64), 256, 0, stream>>>(
        ys1_h, wlin1_h, b_lin1, pooled, xln, SS * BB, DD, HH);

    // 9) LayerNorm + head
    ln_head_kernel<<<BB * SS, 256, 0, stream>>>(xln, gamma, beta, W_head, b_head, out);
}